// Round 2
// baseline (250.182 us; speedup 1.0000x reference)
//
#include <hip/hip_runtime.h>
#include <math.h>

#define N_NODES 50000
#define N_EDGES 800000
#define NE_TOT  (N_EDGES + N_NODES)   // edges + self-loops
#define IN_DIM  128
#define H1 2
#define C1 16
#define D1 (H1*C1)   // 32
#define D2 64        // H2=1, C2=64
#define SLOPE 0.2f
#define CAP 64       // ELL row capacity; max degree ~ Poisson(16)+1 ~ 41 << 64

#define GROUPS 8
#define GRANGE (N_NODES / GROUPS)      // 6250 dst nodes per group
#define SB_PER_G 208                   // scatter blocks per group
#define SCAT_TOT (GROUPS * SB_PER_G)   // 1664
#define SCAT_STRIDE (SB_PER_G * 256)   // 53248 edges per group-sweep step
#define G1_ROWS 64                     // gemm1 rows per block
#define G1_BLK  ((N_NODES + G1_ROWS - 1) / G1_ROWS)   // 782 (last block ragged)

__device__ __forceinline__ float lrelu(float v) { return v > 0.f ? v : SLOPE * v; }

// acc += xs * wv, elementwise on float4 (function, NOT macro: a macro param
// named `w` captured the `.w` member token and broke compilation)
__device__ __forceinline__ void fma4(float4& a, float xs, const float4& wv) {
    a.x += xs * wv.x; a.y += xs * wv.y; a.z += xs * wv.z; a.w += xs * wv.w;
}

// ---- mega: XCD-partitioned ELL scatter ∥ register-tiled gemm1+scores1 ----
// Scatter: group g = blockIdx&7 (round-robin XCD heuristic) owns dst range
// [g*GRANGE,(g+1)*GRANGE). Unchanged from prior version.
// gemm1: NO LDS (keeps scatter blocks at full occupancy). 256 threads =
// 32 row-pairs x 8 col-quads; each thread computes a 2x4 register tile with
// float4 loads of x (one-touch streaming) and W (L1-resident, 16KB).
__global__ void mega_scatter_gemm1(const int* __restrict__ ei,
                                   int* __restrict__ cursor,   // zeroed; ends as deg
                                   int* __restrict__ slots,    // [N_NODES][CAP]
                                   const float* __restrict__ x,
                                   const float* __restrict__ W,
                                   const float* __restrict__ a_src,
                                   const float* __restrict__ a_dst,
                                   float* __restrict__ h,      // [N,32]
                                   float* __restrict__ s,      // [N,2]
                                   float* __restrict__ d) {    // [N,2]
    if (blockIdx.x < SCAT_TOT) {
        int g   = blockIdx.x & 7;
        int ord = blockIdx.x >> 3;              // 0..SB_PER_G-1
        int lo  = g * GRANGE;
        for (int e = ord * 256 + threadIdx.x; e < NE_TOT; e += SCAT_STRIDE) {
            int dst = (e < N_EDGES) ? ei[N_EDGES + e] : (e - N_EDGES);
            if ((unsigned)(dst - lo) < (unsigned)GRANGE) {
                int src = (e < N_EDGES) ? ei[e] : dst;
                int pos = atomicAdd(&cursor[dst], 1);
                if (pos < CAP) slots[(dst << 6) + pos] = src;
            }
        }
        return;
    }
    // ---- gemm1: h1 = x @ W1  [50000,128]x[128,32], register-tiled 2x4 ----
    int blk = blockIdx.x - SCAT_TOT;            // 0..G1_BLK-1
    int t  = threadIdx.x;
    int tx = t & 7;                             // col quad: c0 = 4*tx
    int ty = t >> 3;                            // row pair:  r0 = 2*ty
    int c0 = tx << 2;
    int r0 = blk * G1_ROWS + (ty << 1);
    if (r0 >= N_NODES) return;                  // ragged last block (whole waves exit)
    const float4* xa4 = (const float4*)(x + (long long)r0 * IN_DIM);
    const float4* xb4 = (const float4*)(x + (long long)(r0 + 1) * IN_DIM);
    const float4* W4  = (const float4*)W;       // W[k][32] -> 8 float4 per k-row
    float4 acc0 = {0.f, 0.f, 0.f, 0.f};
    float4 acc1 = {0.f, 0.f, 0.f, 0.f};
#pragma unroll 4
    for (int k = 0; k < IN_DIM; k += 4) {
        float4 xa = xa4[k >> 2];                // rows touched by exactly one lane-octet
        float4 xb = xb4[k >> 2];
        float4 w0 = W4[(k + 0) * 8 + tx];
        float4 w1 = W4[(k + 1) * 8 + tx];
        float4 w2 = W4[(k + 2) * 8 + tx];
        float4 w3 = W4[(k + 3) * 8 + tx];
        fma4(acc0, xa.x, w0); fma4(acc0, xa.y, w1);
        fma4(acc0, xa.z, w2); fma4(acc0, xa.w, w3);
        fma4(acc1, xb.x, w0); fma4(acc1, xb.y, w1);
        fma4(acc1, xb.z, w2); fma4(acc1, xb.w, w3);
    }
    *(float4*)(h + (long long)r0 * D1 + c0)       = acc0;
    *(float4*)(h + (long long)(r0 + 1) * D1 + c0) = acc1;
    // scores1 epilogue: per-head dot with att vectors.
    // c0..c0+3 lies inside one head (head boundary at 16, c0 multiple of 4).
    float4 as = *(const float4*)(a_src + c0);
    float4 ad = *(const float4*)(a_dst + c0);
    float p0 = acc0.x*as.x + acc0.y*as.y + acc0.z*as.z + acc0.w*as.w;
    float q0 = acc0.x*ad.x + acc0.y*ad.y + acc0.z*ad.z + acc0.w*ad.w;
    float p1 = acc1.x*as.x + acc1.y*as.y + acc1.z*as.z + acc1.w*as.w;
    float q1 = acc1.x*ad.x + acc1.y*ad.y + acc1.z*ad.z + acc1.w*ad.w;
    // reduce across the 4 col-quads of each head (tx 0..3 = head0, 4..7 = head1);
    // tx is the low 3 bits of the lane id, so xor 1,2 stays in-group.
    p0 += __shfl_xor(p0, 1); p0 += __shfl_xor(p0, 2);
    q0 += __shfl_xor(q0, 1); q0 += __shfl_xor(q0, 2);
    p1 += __shfl_xor(p1, 1); p1 += __shfl_xor(p1, 2);
    q1 += __shfl_xor(q1, 1); q1 += __shfl_xor(q1, 2);
    if ((tx & 3) == 0) {
        int hd = tx >> 2;
        s[r0 * 2 + hd] = p0;        d[r0 * 2 + hd] = q0;
        s[(r0 + 1) * 2 + hd] = p1;  d[(r0 + 1) * 2 + hd] = q1;
    }
}

// === fused layer 1 + gemm2 + scores2 ===
// Phases A-C: R6's bit-stable LDS-staging softmax/aggregate (ELL addressing).
// Epilogue: ELU -> LDS (same-wave RAW, no barrier), then each of the 64 lanes
// computes one h2 column with the identical ascending-k loop gemm2 used, and
// a 64-lane butterfly produces s2/d2. agg1 never touches global memory.
__global__ void fused_l1_gemm2(const int* __restrict__ cur,
                               const int* __restrict__ slots,
                               const float* __restrict__ s,   // [N,2]
                               const float* __restrict__ d,   // [N,2]
                               const float* __restrict__ h,   // [N,32]
                               const float* __restrict__ bias,
                               const float* __restrict__ W2,  // [32,64]
                               const float* __restrict__ a2s, // [64]
                               const float* __restrict__ a2d, // [64]
                               float* __restrict__ h2,        // [N,64]
                               float* __restrict__ s2,        // [N]
                               float* __restrict__ d2) {      // [N]
    __shared__ float sW2[D1 * D2];                  // 8 KB
    __shared__ int   sh_sn[4][64];
    __shared__ float sh_p0[4][64];
    __shared__ float sh_p1[4][64];
    int t = threadIdx.x;
    for (int i = t; i < D1 * D2; i += 256) sW2[i] = W2[i];
    __syncthreads();
    int wave = t >> 6;
    int node = blockIdx.x * 4 + wave;               // grid exact: 12500*4
    int lane = t & 63;
    int deg = cur[node]; if (deg > CAP) deg = CAP;
    int start = node << 6, end = start + deg;
    float2 dn = ((const float2*)d)[node];
    // phase A: per-head segment max
    float m0 = -INFINITY, m1 = -INFINITY;
    for (int k = start + lane; k < end; k += 64) {
        float2 sv = ((const float2*)s)[slots[k]];
        m0 = fmaxf(m0, lrelu(sv.x + dn.x));
        m1 = fmaxf(m1, lrelu(sv.y + dn.y));
    }
    for (int o = 32; o; o >>= 1) {
        m0 = fmaxf(m0, __shfl_xor(m0, o));
        m1 = fmaxf(m1, __shfl_xor(m1, o));
    }
    // phase B: z-sum + LDS staging of per-edge pe
    float z0 = 0.f, z1 = 0.f;
    int k0 = start + lane;
    if (k0 < end) {
        int sn = slots[k0];
        float2 sv = ((const float2*)s)[sn];
        float p0 = expf(lrelu(sv.x + dn.x) - m0);
        float p1 = expf(lrelu(sv.y + dn.y) - m1);
        sh_sn[wave][lane] = sn;
        sh_p0[wave][lane] = p0;
        sh_p1[wave][lane] = p1;
        z0 = p0; z1 = p1;
    }
    for (int o = 32; o; o >>= 1) {
        z0 += __shfl_xor(z0, o);
        z1 += __shfl_xor(z1, o);
    }
    // phase C: channel-parallel accumulate, halves on even/odd edges
    int ch = lane & 31;
    int half = lane >> 5;
    int hd = ch >> 4;
    float acc = 0.f;
    for (int j = half; j < deg; j += 2) {
        float p = hd ? sh_p1[wave][j] : sh_p0[wave][j];
        acc += p * h[sh_sn[wave][j] * 32 + ch];
    }
    acc += __shfl_xor(acc, 32);
    // epilogue: normalize + bias + ELU -> LDS (reuse sh_p0 slice)
    if (lane < 32) {
        float zz = hd ? z1 : z0;
        float v = acc / (zz + 1e-16f) + bias[ch];
        sh_p0[wave][ch] = v > 0.f ? v : expf(v) - 1.f;   // ELU
    }
    // gemm2 (same-wave LDS RAW -> compiler-inserted lgkmcnt, no barrier)
    float hc = 0.f;
#pragma unroll
    for (int k = 0; k < D1; ++k) hc += sh_p0[wave][k] * sW2[k * D2 + lane];
    h2[node * 64 + lane] = hc;
    // scores2: 64-lane butterfly
    float p = hc * a2s[lane];
    float q = hc * a2d[lane];
#pragma unroll
    for (int o = 32; o; o >>= 1) { p += __shfl_xor(p, o); q += __shfl_xor(q, o); }
    if (lane == 0) { s2[node] = p; d2[node] = q; }
}

// ============ fused layer 2: softmax + aggregate + norm + bias ===============
__global__ void fused_layer2(const int* __restrict__ cur,
                             const int* __restrict__ slots,
                             const float* __restrict__ s,   // [N]
                             const float* __restrict__ d,   // [N]
                             const float* __restrict__ h,   // [N,64]
                             const float* __restrict__ bias,
                             float* __restrict__ out) {     // [N,64] final
    __shared__ int   sh_sn[4][64];
    __shared__ float sh_pe[4][64];
    int wave = threadIdx.x >> 6;
    int node = blockIdx.x * 4 + wave;
    if (node >= N_NODES) return;
    int lane = threadIdx.x & 63;
    int deg = cur[node]; if (deg > CAP) deg = CAP;
    int start = node << 6, end = start + deg;
    float dn = d[node];
    // phase A: segment max
    float m = -INFINITY;
    for (int k = start + lane; k < end; k += 64)
        m = fmaxf(m, lrelu(s[slots[k]] + dn));
    for (int o = 32; o; o >>= 1) m = fmaxf(m, __shfl_xor(m, o));
    // phase B: z-sum + LDS staging of per-edge pe
    float z = 0.f;
    int k0 = start + lane;
    if (k0 < end) {
        int sn = slots[k0];
        float pe = expf(lrelu(s[sn] + dn) - m);
        sh_sn[wave][lane] = sn;
        sh_pe[wave][lane] = pe;
        z = pe;
    }
    for (int o = 32; o; o >>= 1) z += __shfl_xor(z, o);
    // phase C: lane = channel; staged scalars, sequential edge order
    float acc = 0.f;
    for (int j = 0; j < deg; ++j) {
        acc += sh_pe[wave][j] * h[sh_sn[wave][j] * 64 + lane];
    }
    out[node * 64 + lane] = acc / (z + 1e-16f) + bias[lane];
}

extern "C" void kernel_launch(void* const* d_in, const int* in_sizes, int n_in,
                              void* d_out, int out_size, void* d_ws, size_t ws_size,
                              hipStream_t stream) {
    const float* x        = (const float*)d_in[0];
    const int*   ei       = (const int*)  d_in[1];   // [2, N_EDGES] int32
    const float* W1       = (const float*)d_in[2];
    const float* att_src1 = (const float*)d_in[3];
    const float* att_dst1 = (const float*)d_in[4];
    const float* bias1    = (const float*)d_in[5];
    const float* W2       = (const float*)d_in[6];
    const float* att_src2 = (const float*)d_in[7];
    const float* att_dst2 = (const float*)d_in[8];
    const float* bias2    = (const float*)d_in[9];
    float* out = (float*)d_out;

    // workspace layout
    float* w    = (float*)d_ws;
    float* h1   = w; w += (long long)N_NODES * D1;   // 1.6M f
    float* s1   = w; w += N_NODES * H1;
    float* d1v  = w; w += N_NODES * H1;
    float* h2   = w; w += (long long)N_NODES * D2;   // 3.2M f
    float* s2   = w; w += N_NODES;
    float* d2v  = w; w += N_NODES;
    int* iw     = (int*)w;
    int* cursor = iw; iw += N_NODES;                 // degree counters
    int* slots  = iw; iw += (long long)N_NODES * CAP; // ELL: 3.2M i (12.8 MB)

    const int B = 256;
    (void)hipMemsetAsync(cursor, 0, N_NODES * sizeof(int), stream);
    mega_scatter_gemm1<<<SCAT_TOT + G1_BLK, B, 0, stream>>>(
        ei, cursor, slots, x, W1, att_src1, att_dst1, h1, s1, d1v);
    fused_l1_gemm2<<<N_NODES / 4, B, 0, stream>>>(
        cursor, slots, s1, d1v, h1, bias1, W2, att_src2, att_dst2, h2, s2, d2v);
    fused_layer2<<<(N_NODES + 3)/4, B, 0, stream>>>(cursor, slots, s2, d2v, h2, bias2, out);
}

// Round 3
// 234.401 us; speedup vs baseline: 1.0673x; 1.0673x over previous
//
#include <hip/hip_runtime.h>
#include <math.h>

#define N_NODES 50000
#define N_EDGES 800000
#define IN_DIM  128
#define H1 2
#define C1 16
#define D1 (H1*C1)   // 32
#define D2 64        // H2=1, C2=64
#define SLOPE 0.2f
#define CAP 64       // ELL row capacity; max degree ~ Poisson(16)+1 ~ 41 << 64

#define GROUPS 8
#define GRANGE (N_NODES / GROUPS)      // 6250 dst nodes per group
#define SB_PER_G 208                   // scatter blocks per group
#define SCAT_TOT (GROUPS * SB_PER_G)   // 1664
#define SCAN_T   (SB_PER_G * 256)      // 53248 scan threads per group
#define G1_ROWS 64                     // gemm1 rows per block
#define G1_BLK  ((N_NODES + G1_ROWS - 1) / G1_ROWS)   // 782 (last block ragged)

__device__ __forceinline__ float lrelu(float v) { return v > 0.f ? v : SLOPE * v; }

// acc += xs * wv, elementwise on float4 (function, NOT macro)
__device__ __forceinline__ void fma4(float4& a, float xs, const float4& wv) {
    a.x += xs * wv.x; a.y += xs * wv.y; a.z += xs * wv.z; a.w += xs * wv.w;
}

// ---- init: cursor=1, self-loop pre-seeded at slot 0 (replaces memset) ----
__global__ void init_ell(int* __restrict__ cursor, int* __restrict__ slots) {
    int n = blockIdx.x * 256 + threadIdx.x;
    if (n < N_NODES) { cursor[n] = 1; slots[n << 6] = n; }
}

// ---- mega: XCD-partitioned ELL scatter ∥ register-tiled gemm1+scores1 ----
// Scatter: group g = blockIdx&7 (round-robin XCD heuristic) owns dst range
// [g*GRANGE,(g+1)*GRANGE). Scan is int4-vectorized: each thread covers
// 4 sweeps x int4 = 16 edges with 4 outstanding 16B dst loads (4x MLP vs
// the old scalar scan). Self-loops no longer scanned (pre-seeded).
__global__ void mega_scatter_gemm1(const int* __restrict__ ei,
                                   int* __restrict__ cursor,   // init=1; ends as deg
                                   int* __restrict__ slots,    // [N_NODES][CAP]
                                   const float* __restrict__ x,
                                   const float* __restrict__ W,
                                   const float* __restrict__ a_src,
                                   const float* __restrict__ a_dst,
                                   float* __restrict__ h,      // [N,32]
                                   float* __restrict__ s,      // [N,2]
                                   float* __restrict__ d) {    // [N,2]
    if (blockIdx.x < SCAT_TOT) {
        int g   = blockIdx.x & 7;
        int ord = blockIdx.x >> 3;              // 0..SB_PER_G-1
        int lo  = g * GRANGE;
        int tg  = ord * 256 + threadIdx.x;      // 0..SCAN_T-1
        const int4* dst4 = (const int4*)(ei + N_EDGES);
#pragma unroll
        for (int w = 0; w < 4; ++w) {
            int base = (w * SCAN_T + tg) << 2;  // 4 consecutive edges
            if (base >= N_EDGES) break;         // N_EDGES%4==0 -> all-or-nothing
            int4 dv = dst4[base >> 2];
            int dd[4] = {dv.x, dv.y, dv.z, dv.w};
#pragma unroll
            for (int j = 0; j < 4; ++j) {
                if ((unsigned)(dd[j] - lo) < (unsigned)GRANGE) {
                    int src = ei[base + j];
                    int pos = atomicAdd(&cursor[dd[j]], 1);
                    if (pos < CAP) slots[(dd[j] << 6) + pos] = src;
                }
            }
        }
        return;
    }
    // ---- gemm1: h1 = x @ W1  [50000,128]x[128,32], register-tiled 2x4 ----
    int blk = blockIdx.x - SCAT_TOT;            // 0..G1_BLK-1
    int t  = threadIdx.x;
    int tx = t & 7;                             // col quad: c0 = 4*tx
    int ty = t >> 3;                            // row pair:  r0 = 2*ty
    int c0 = tx << 2;
    int r0 = blk * G1_ROWS + (ty << 1);
    if (r0 >= N_NODES) return;                  // ragged last block (whole waves exit)
    const float4* xa4 = (const float4*)(x + (long long)r0 * IN_DIM);
    const float4* xb4 = (const float4*)(x + (long long)(r0 + 1) * IN_DIM);
    const float4* W4  = (const float4*)W;       // W[k][32] -> 8 float4 per k-row
    float4 acc0 = {0.f, 0.f, 0.f, 0.f};
    float4 acc1 = {0.f, 0.f, 0.f, 0.f};
#pragma unroll 4
    for (int k = 0; k < IN_DIM; k += 4) {
        float4 xa = xa4[k >> 2];
        float4 xb = xb4[k >> 2];
        float4 w0 = W4[(k + 0) * 8 + tx];
        float4 w1 = W4[(k + 1) * 8 + tx];
        float4 w2 = W4[(k + 2) * 8 + tx];
        float4 w3 = W4[(k + 3) * 8 + tx];
        fma4(acc0, xa.x, w0); fma4(acc0, xa.y, w1);
        fma4(acc0, xa.z, w2); fma4(acc0, xa.w, w3);
        fma4(acc1, xb.x, w0); fma4(acc1, xb.y, w1);
        fma4(acc1, xb.z, w2); fma4(acc1, xb.w, w3);
    }
    *(float4*)(h + (long long)r0 * D1 + c0)       = acc0;
    *(float4*)(h + (long long)(r0 + 1) * D1 + c0) = acc1;
    // scores1 epilogue: per-head dot with att vectors.
    float4 as = *(const float4*)(a_src + c0);
    float4 ad = *(const float4*)(a_dst + c0);
    float p0 = acc0.x*as.x + acc0.y*as.y + acc0.z*as.z + acc0.w*as.w;
    float q0 = acc0.x*ad.x + acc0.y*ad.y + acc0.z*ad.z + acc0.w*ad.w;
    float p1 = acc1.x*as.x + acc1.y*as.y + acc1.z*as.z + acc1.w*as.w;
    float q1 = acc1.x*ad.x + acc1.y*ad.y + acc1.z*ad.z + acc1.w*ad.w;
    p0 += __shfl_xor(p0, 1); p0 += __shfl_xor(p0, 2);
    q0 += __shfl_xor(q0, 1); q0 += __shfl_xor(q0, 2);
    p1 += __shfl_xor(p1, 1); p1 += __shfl_xor(p1, 2);
    q1 += __shfl_xor(q1, 1); q1 += __shfl_xor(q1, 2);
    if ((tx & 3) == 0) {
        int hd = tx >> 2;
        s[r0 * 2 + hd] = p0;        d[r0 * 2 + hd] = q0;
        s[(r0 + 1) * 2 + hd] = p1;  d[(r0 + 1) * 2 + hd] = q1;
    }
}

// === fused layer 1 + gemm2 + scores2 ===
// deg <= CAP = 64, so each lane owns at most ONE edge: gather s[slots[k]]
// exactly once into registers, reuse for both the max (A) and exp/z (B).
__global__ void fused_l1_gemm2(const int* __restrict__ cur,
                               const int* __restrict__ slots,
                               const float* __restrict__ s,   // [N,2]
                               const float* __restrict__ d,   // [N,2]
                               const float* __restrict__ h,   // [N,32]
                               const float* __restrict__ bias,
                               const float* __restrict__ W2,  // [32,64]
                               const float* __restrict__ a2s, // [64]
                               const float* __restrict__ a2d, // [64]
                               float* __restrict__ h2,        // [N,64]
                               float* __restrict__ s2,        // [N]
                               float* __restrict__ d2) {      // [N]
    __shared__ float sW2[D1 * D2];                  // 8 KB
    __shared__ int   sh_sn[4][64];
    __shared__ float sh_p0[4][64];
    __shared__ float sh_p1[4][64];
    int t = threadIdx.x;
    for (int i = t; i < D1 * D2; i += 256) sW2[i] = W2[i];
    __syncthreads();
    int wave = t >> 6;
    int node = blockIdx.x * 4 + wave;               // grid exact: 12500*4
    int lane = t & 63;
    int deg = cur[node]; if (deg > CAP) deg = CAP;
    int start = node << 6;
    float2 dn = ((const float2*)d)[node];
    // phase A+B fused: one gather per edge, kept in registers
    int sn = 0;
    float e0 = -INFINITY, e1 = -INFINITY;
    bool has = lane < deg;
    if (has) {
        sn = slots[start + lane];
        float2 sv = ((const float2*)s)[sn];
        e0 = lrelu(sv.x + dn.x);
        e1 = lrelu(sv.y + dn.y);
    }
    float m0 = e0, m1 = e1;
    for (int o = 32; o; o >>= 1) {
        m0 = fmaxf(m0, __shfl_xor(m0, o));
        m1 = fmaxf(m1, __shfl_xor(m1, o));
    }
    float z0 = 0.f, z1 = 0.f;
    if (has) {
        float p0 = expf(e0 - m0);
        float p1 = expf(e1 - m1);
        sh_sn[wave][lane] = sn;
        sh_p0[wave][lane] = p0;
        sh_p1[wave][lane] = p1;
        z0 = p0; z1 = p1;
    }
    for (int o = 32; o; o >>= 1) {
        z0 += __shfl_xor(z0, o);
        z1 += __shfl_xor(z1, o);
    }
    // phase C: channel-parallel accumulate, halves on even/odd edges
    int ch = lane & 31;
    int half = lane >> 5;
    int hd = ch >> 4;
    float acc = 0.f;
    for (int j = half; j < deg; j += 2) {
        float p = hd ? sh_p1[wave][j] : sh_p0[wave][j];
        acc += p * h[sh_sn[wave][j] * 32 + ch];
    }
    acc += __shfl_xor(acc, 32);
    // epilogue: normalize + bias + ELU -> LDS (reuse sh_p0 slice)
    if (lane < 32) {
        float zz = hd ? z1 : z0;
        float v = acc / (zz + 1e-16f) + bias[ch];
        sh_p0[wave][ch] = v > 0.f ? v : expf(v) - 1.f;   // ELU
    }
    // gemm2 (same-wave LDS RAW -> compiler-inserted lgkmcnt, no barrier)
    float hc = 0.f;
#pragma unroll
    for (int k = 0; k < D1; ++k) hc += sh_p0[wave][k] * sW2[k * D2 + lane];
    h2[node * 64 + lane] = hc;
    // scores2: 64-lane butterfly
    float p = hc * a2s[lane];
    float q = hc * a2d[lane];
#pragma unroll
    for (int o = 32; o; o >>= 1) { p += __shfl_xor(p, o); q += __shfl_xor(q, o); }
    if (lane == 0) { s2[node] = p; d2[node] = q; }
}

// ============ fused layer 2: softmax + aggregate + norm + bias ===============
__global__ void fused_layer2(const int* __restrict__ cur,
                             const int* __restrict__ slots,
                             const float* __restrict__ s,   // [N]
                             const float* __restrict__ d,   // [N]
                             const float* __restrict__ h,   // [N,64]
                             const float* __restrict__ bias,
                             float* __restrict__ out) {     // [N,64] final
    __shared__ int   sh_sn[4][64];
    __shared__ float sh_pe[4][64];
    int wave = threadIdx.x >> 6;
    int node = blockIdx.x * 4 + wave;
    if (node >= N_NODES) return;
    int lane = threadIdx.x & 63;
    int deg = cur[node]; if (deg > CAP) deg = CAP;
    int start = node << 6;
    float dn = d[node];
    // phase A+B fused: one gather per edge, kept in registers
    int sn = 0;
    float ev = -INFINITY;
    bool has = lane < deg;
    if (has) {
        sn = slots[start + lane];
        ev = lrelu(s[sn] + dn);
    }
    float m = ev;
    for (int o = 32; o; o >>= 1) m = fmaxf(m, __shfl_xor(m, o));
    float z = 0.f;
    if (has) {
        float pe = expf(ev - m);
        sh_sn[wave][lane] = sn;
        sh_pe[wave][lane] = pe;
        z = pe;
    }
    for (int o = 32; o; o >>= 1) z += __shfl_xor(z, o);
    // phase C: lane = channel; staged scalars, sequential edge order
    float acc = 0.f;
    for (int j = 0; j < deg; ++j) {
        acc += sh_pe[wave][j] * h[sh_sn[wave][j] * 64 + lane];
    }
    out[node * 64 + lane] = acc / (z + 1e-16f) + bias[lane];
}

extern "C" void kernel_launch(void* const* d_in, const int* in_sizes, int n_in,
                              void* d_out, int out_size, void* d_ws, size_t ws_size,
                              hipStream_t stream) {
    const float* x        = (const float*)d_in[0];
    const int*   ei       = (const int*)  d_in[1];   // [2, N_EDGES] int32
    const float* W1       = (const float*)d_in[2];
    const float* att_src1 = (const float*)d_in[3];
    const float* att_dst1 = (const float*)d_in[4];
    const float* bias1    = (const float*)d_in[5];
    const float* W2       = (const float*)d_in[6];
    const float* att_src2 = (const float*)d_in[7];
    const float* att_dst2 = (const float*)d_in[8];
    const float* bias2    = (const float*)d_in[9];
    float* out = (float*)d_out;

    // workspace layout
    float* w    = (float*)d_ws;
    float* h1   = w; w += (long long)N_NODES * D1;   // 1.6M f
    float* s1   = w; w += N_NODES * H1;
    float* d1v  = w; w += N_NODES * H1;
    float* h2   = w; w += (long long)N_NODES * D2;   // 3.2M f
    float* s2   = w; w += N_NODES;
    float* d2v  = w; w += N_NODES;
    int* iw     = (int*)w;
    int* cursor = iw; iw += N_NODES;                 // degree counters
    int* slots  = iw; iw += (long long)N_NODES * CAP; // ELL: 3.2M i (12.8 MB)

    const int B = 256;
    init_ell<<<(N_NODES + 255)/256, B, 0, stream>>>(cursor, slots);
    mega_scatter_gemm1<<<SCAT_TOT + G1_BLK, B, 0, stream>>>(
        ei, cursor, slots, x, W1, att_src1, att_dst1, h1, s1, d1v);
    fused_l1_gemm2<<<N_NODES / 4, B, 0, stream>>>(
        cursor, slots, s1, d1v, h1, bias1, W2, att_src2, att_dst2, h2, s2, d2v);
    fused_layer2<<<(N_NODES + 3)/4, B, 0, stream>>>(cursor, slots, s2, d2v, h2, bias2, out);
}